// Round 11
// baseline (432.047 us; speedup 1.0000x reference)
//
#include <hip/hip_runtime.h>
#include <hip/hip_bf16.h>
#include <hip/hip_cooperative_groups.h>

namespace cg = cooperative_groups;

#define N_NODES 10000
#define N_EDGES 320000
#define N_REL   460
#define N_BASES 30
#define DIM     200
#define KZ      6016   // 30*200=6000 padded to multiple of 32
#define KT      6240   // KZ + 224 (self-term columns appended)
#define NSTEPS  195    // KT/32
#define NTILES  157    // ceil(10000/64)
#define NFRAG   16     // col fragments of 16 (13 real, 3 zero-padded)
#define KSPLIT  6
#define PROWS   10048  // 157*64
#define TKELEM  2048   // ASW elements per (tile,kstep): 4 sub x 16 rows x 32 cols

#define PREP_B8 (NFRAG * NSTEPS * 64)    // 199680 (8 elems/thread)
#define PREP_C  (N_REL * 16)             // 7360
#define PREP_X8 (N_NODES * 28)           // 280000 (28 pair-tasks/node)

using short8  = __attribute__((ext_vector_type(8))) short;
using s4v     = __attribute__((ext_vector_type(4))) short;
using floatx4 = __attribute__((ext_vector_type(4))) float;

__device__ __forceinline__ unsigned short f2bf(float f) {
    union { float f; unsigned u; } v; v.f = f;
    unsigned u = v.u;
    return (unsigned short)((u + 0x7fffu + ((u >> 16) & 1u)) >> 16);
}

__device__ __forceinline__ short8 pack8(const unsigned short* u) {
    union { unsigned short s[8]; short8 v; } p;
#pragma unroll
    for (int i = 0; i < 8; ++i) p.s[i] = u[i];
    return p.v;
}

// ASW v3: 64-row tiles. Element (node n, col c):
//   t=n>>6, sub=(n>>4)&3, rl=n&15; kk=c>>5, w=c&31
//   idx = (t*195+kk)*2048 + sub*512 + rl*32 + w
__device__ __forceinline__ size_t asw_idx(int n, int c) {
    int t = n >> 6, sub = (n >> 4) & 3, rl = n & 15;
    int kk = c >> 5, w = c & 31;
    return (size_t)(t * NSTEPS + kk) * TKELEM + sub * 512 + rl * 32 + w;
}

// ---------------- fused sort: zero -> hist(+BSW,Cpair) -> scan -> scatter(+Xprep) ----
// R24: replaces memset + sort1 + scan + sort2 (4 dispatches -> 1 cooperative
// launch). The invisible ~143 us of the pipeline is partly per-dispatch
// overhead; phase bodies are verbatim from the passing R10 kernels
// (grid-stride re-indexed) -> numerics identical. 512 blocks x 256 threads:
// trivially co-resident (light VGPR, 1 KB LDS), grid.sync between phases.

__global__ __launch_bounds__(256) void fused_sort_kernel(
    const int* __restrict__ src, const int* __restrict__ tgt,
    const int* __restrict__ etype,
    const float* __restrict__ x, const float* __restrict__ weight,
    const float* __restrict__ sw, const float* __restrict__ coeff,
    int* deg, int* starts, int* cursor, float* dinv, int2* sedge,
    unsigned short* __restrict__ XbfP, unsigned short* __restrict__ ASW,
    unsigned short* __restrict__ BSW, unsigned int* __restrict__ Cpair)
{
    cg::grid_group grid = cg::this_grid();
    int gsz = gridDim.x * blockDim.x;
    int gid = blockIdx.x * blockDim.x + threadIdx.x;

    // phase 0: zero deg
    for (int i = gid; i < N_NODES; i += gsz) deg[i] = 0;
    grid.sync();

    // phase 1: hist + independent preps (BSW, Cpair)
    for (int i = gid; i < N_EDGES; i += gsz) atomicAdd(&deg[tgt[i]], 1);
    for (int i = gid; i < PREP_B8; i += gsz) {
        int f = i / (NSTEPS * 64);
        int rem = i - f * (NSTEPS * 64);
        int kk = rem >> 6;
        int l = rem & 63;
        int rB = f * 16 + (l & 15);
        int kbase = kk * 32 + (l >> 4) * 8;
        unsigned short bs[8];
#pragma unroll
        for (int j = 0; j < 8; ++j) {
            int k = kbase + j;
            float v = 0.f;
            if (rB < DIM) {
                if (k < KZ) {
                    if (k < N_BASES * DIM) {
                        int b = k / DIM, kc = k - b * DIM;
                        v = weight[(b * DIM + kc) * DIM + rB];
                    }
                } else {
                    int jj = k - KZ;
                    if (jj < DIM) v = sw[jj * DIM + rB];
                }
            }
            bs[j] = f2bf(v);
        }
        *(short8*)(BSW + (size_t)i * 8) = pack8(bs);
    }
    for (int i = gid; i < PREP_C; i += gsz) {
        int t = i >> 4, m = i & 15;
        unsigned lo = f2bf(coeff[t * N_BASES + m]);
        unsigned hi = (m + 16 < N_BASES) ? f2bf(coeff[t * N_BASES + m + 16]) : 0u;
        Cpair[i] = lo | (hi << 16);
    }
    grid.sync();

    // phase 2: block-0 scan (256 threads x 40 nodes)
    if (blockIdx.x == 0) {
        __shared__ int part2[256];
        int tid = threadIdx.x;
        const int PER = 40;                 // 256*40 = 10240 >= 10000
        int base = tid * PER;
        int s = 0;
        for (int i = 0; i < PER; ++i) { int k = base + i; if (k < N_NODES) s += deg[k]; }
        part2[tid] = s; __syncthreads();
        for (int off = 1; off < 256; off <<= 1) {
            int v = (tid >= off) ? part2[tid - off] : 0;
            __syncthreads();
            part2[tid] += v;
            __syncthreads();
        }
        int run = (tid > 0) ? part2[tid - 1] : 0;
        for (int i = 0; i < PER; ++i) {
            int k = base + i;
            if (k < N_NODES) {
                int d = deg[k];
                starts[k] = run; cursor[k] = run;
                dinv[k] = 1.0f / (float)(d > 0 ? d : 1);
                run += d;
            }
        }
        if (tid == 255) starts[N_NODES] = part2[255];
    }
    grid.sync();

    // phase 3: scatter + paired-X prep (R23 layout: XbfP slot (p,c) holds
    // (x[n][p*32+c], x[n][p*32+16+c]) as (lo,hi) bf16; ASW self cols deg*x)
    for (int i = gid; i < N_EDGES; i += gsz) {
        int t = tgt[i];
        int pos = atomicAdd(&cursor[t], 1);
        sedge[pos] = make_int2(src[i], etype[i]);
    }
    for (int i = gid; i < PREP_X8; i += gsz) {
        int n = i / 28, t = i - n * 28;
        int p = t >> 2, c4 = (t & 3) << 2;
        int cl = p * 32 + c4;
        int ch = cl + 16;
        int d = deg[n]; if (d < 1) d = 1;
        float df = (float)d;
        floatx4 vlo = (floatx4){0.f, 0.f, 0.f, 0.f};
        floatx4 vhi = (floatx4){0.f, 0.f, 0.f, 0.f};
        if (cl < DIM) vlo = *(const floatx4*)(x + (size_t)n * DIM + cl);
        if (ch < DIM) vhi = *(const floatx4*)(x + (size_t)n * DIM + ch);
        unsigned short xp[8], asl[4], ash[4];
#pragma unroll
        for (int k = 0; k < 4; ++k) {
            xp[2 * k]     = f2bf(vlo[k]);
            xp[2 * k + 1] = f2bf(vhi[k]);
            asl[k] = f2bf(df * vlo[k]);
            ash[k] = f2bf(df * vhi[k]);
        }
        *(short8*)(XbfP + (size_t)n * 224 + p * 32 + c4 * 2) = pack8(xp);
        union { unsigned short s[4]; s4v v; } ul, uh;
#pragma unroll
        for (int k = 0; k < 4; ++k) { ul.s[k] = asl[k]; uh.s[k] = ash[k]; }
        *(s4v*)(ASW + asw_idx(n, KZ + cl)) = ul.v;
        *(s4v*)(ASW + asw_idx(n, KZ + ch)) = uh.v;
    }
}

// ---------------- per-target-node aggregation via MFMA ----------------
// R23 (kept): R6's proven double-buffered gather over PAIRED X: one u32 load
// feeds frags f=2p (lo16) and f=2p+1 (hi16). MFMA set per accumulator
// identical to R6 => numerics unchanged.

__global__ __launch_bounds__(256) void agg_kernel(const unsigned int* __restrict__ XbfP,
                                                  const unsigned int* __restrict__ Cpair,
                                                  const int* __restrict__ starts,
                                                  const int2* __restrict__ sedge,
                                                  unsigned short* __restrict__ ASW) {
    __shared__ __align__(16) unsigned short zbuf[4][3232];  // 25856 B/block
    int lane = threadIdx.x & 63;
    int wave = threadIdx.x >> 6;
    int n = blockIdx.x * 4 + wave;            // 2500*4 == 10000 exactly
    int ln = lane & 15, q = lane >> 4;

    floatx4 acc0[13], acc1[13];
#pragma unroll
    for (int f = 0; f < 13; ++f) {
        acc0[f] = (floatx4){0.f, 0.f, 0.f, 0.f};
        acc1[f] = acc0[f];
    }

    int e0 = starts[n], e1 = starts[n + 1];
    for (int kb = e0; kb < e1; kb += 32) {
        int eb = kb + 8 * q;
        unsigned short a0v[8], a1v[8];
        int srcs[8];
#pragma unroll
        for (int j = 0; j < 8; ++j) {
            int e = eb + j;
            int ec = (e < e1) ? e : (e1 - 1);
            int2 sd = sedge[ec];
            unsigned cp = (e < e1) ? Cpair[sd.y * 16 + ln] : 0u;
            a0v[j] = (unsigned short)(cp & 0xffffu);
            a1v[j] = (unsigned short)(cp >> 16);
            srcs[j] = sd.x;
        }
        short8 A0 = pack8(a0v), A1 = pack8(a1v);

        unsigned pv[2][8];
#pragma unroll
        for (int j = 0; j < 8; ++j)
            pv[0][j] = XbfP[(size_t)srcs[j] * 112 + ln];
#pragma unroll
        for (int p = 0; p < 7; ++p) {
            int cur = p & 1, nxt = cur ^ 1;
            if (p < 6) {
#pragma unroll
                for (int j = 0; j < 8; ++j)
                    pv[nxt][j] = XbfP[(size_t)srcs[j] * 112 + (p + 1) * 16 + ln];
            }
            unsigned short lo[8], hi[8];
#pragma unroll
            for (int j = 0; j < 8; ++j) {
                lo[j] = (unsigned short)(pv[cur][j] & 0xffffu);
                hi[j] = (unsigned short)(pv[cur][j] >> 16);
            }
            short8 Blo = pack8(lo), Bhi = pack8(hi);
            int f0 = 2 * p;
            acc0[f0] = __builtin_amdgcn_mfma_f32_16x16x32_bf16(A0, Blo, acc0[f0], 0, 0, 0);
            acc1[f0] = __builtin_amdgcn_mfma_f32_16x16x32_bf16(A1, Blo, acc1[f0], 0, 0, 0);
            if (2 * p + 1 < 13) {
                acc0[2 * p + 1] = __builtin_amdgcn_mfma_f32_16x16x32_bf16(A0, Bhi, acc0[2 * p + 1], 0, 0, 0);
                acc1[2 * p + 1] = __builtin_amdgcn_mfma_f32_16x16x32_bf16(A1, Bhi, acc1[2 * p + 1], 0, 0, 0);
            }
        }
    }

    unsigned short* zb = zbuf[wave];
    int t = n >> 6, sub = (n >> 4) & 3, rl = n & 15;
    const uint4* zb4 = (const uint4*)zb;
    uint4* dst = (uint4*)ASW;
    size_t base_u4 = (size_t)t * NSTEPS * 256 + sub * 64 + rl * 4;

    // phase 1: bases 0..15 -> cols [0,3200), ksteps 0..99
#pragma unroll
    for (int f = 0; f < 13; ++f) {
        int d = f * 16 + ln;
        if (d < DIM) {
#pragma unroll
            for (int i = 0; i < 4; ++i)
                zb[(q * 4 + i) * DIM + d] = f2bf(acc0[f][i]);
        }
    }
    for (int v = lane; v < 400; v += 64) {
        int kk = v >> 2, w8 = v & 3;
        dst[base_u4 + (size_t)kk * 256 + w8] = zb4[v];
    }

    // phase 2: bases 16..29 -> cols [3200,6000) + pad, ksteps 100..187
    if (lane < 16) zb[2800 + lane] = 0;
#pragma unroll
    for (int f = 0; f < 13; ++f) {
        int d = f * 16 + ln;
        if (d < DIM) {
#pragma unroll
            for (int i = 0; i < 4; ++i) {
                int b1 = 16 + q * 4 + i;
                if (b1 < N_BASES) zb[(b1 - 16) * DIM + d] = f2bf(acc1[f][i]);
            }
        }
    }
    for (int v = lane; v < 352; v += 64) {
        int kk = 100 + (v >> 2), w8 = v & 3;
        dst[base_u4 + (size_t)kk * 256 + w8] = zb4[v];
    }
}

// ---------------- GEMM: part[chunk] = A_ext @ B_ext^T over K-chunk ----------------
// == R16 exactly (best measured: 56-59 us). A staged via global_load_lds
// (7 ksteps ahead, counted vmcnt, never drained in loop); B double-buffered
// 1 kstep ahead in registers.

#define GITER(VLIT, BU, BL, KK)                                                        \
  {                                                                                    \
    asm volatile("s_waitcnt vmcnt(" #VLIT ")" ::: "memory");                           \
    __builtin_amdgcn_sched_barrier(0);                                                 \
    asm volatile("s_barrier" ::: "memory");                                            \
    const int kk_ = (KK);                                                              \
    const int kld_ = (kk_ + 1 < ke) ? kk_ + 1 : ke - 1;                                \
    BL[0] = *(const short8*)(pb + ((size_t)(0 * 4 * NSTEPS) + kld_) * 512);            \
    BL[1] = *(const short8*)(pb + ((size_t)(1 * 4 * NSTEPS) + kld_) * 512);            \
    BL[2] = *(const short8*)(pb + ((size_t)(2 * 4 * NSTEPS) + kld_) * 512);            \
    BL[3] = *(const short8*)(pb + ((size_t)(3 * 4 * NSTEPS) + kld_) * 512);            \
    const int kst_ = (kk_ + 7 < ke) ? kk_ + 7 : ke - 1;                                \
    __builtin_amdgcn_global_load_lds(                                                  \
        (const unsigned int*)(aswt + (size_t)kst_ * TKELEM + goff),                    \
        (unsigned int*)(ldsw + ((kk_ + 7) & 7) * 2048), 16, 0, 0);                     \
    const unsigned short* sp_ = alds + (kk_ & 7) * 2048 + pread8;                      \
    short8 av0 = *(const short8*)(sp_);                                                \
    short8 av1 = *(const short8*)(sp_ + 512);                                          \
    short8 av2 = *(const short8*)(sp_ + 1024);                                         \
    short8 av3 = *(const short8*)(sp_ + 1536);                                         \
    _Pragma("unroll")                                                                  \
    for (int i_ = 0; i_ < 4; ++i_) {                                                   \
      acc[i_][0] = __builtin_amdgcn_mfma_f32_16x16x32_bf16(av0, BU[i_], acc[i_][0], 0, 0, 0); \
      acc[i_][1] = __builtin_amdgcn_mfma_f32_16x16x32_bf16(av1, BU[i_], acc[i_][1], 0, 0, 0); \
      acc[i_][2] = __builtin_amdgcn_mfma_f32_16x16x32_bf16(av2, BU[i_], acc[i_][2], 0, 0, 0); \
      acc[i_][3] = __builtin_amdgcn_mfma_f32_16x16x32_bf16(av3, BU[i_], acc[i_][3], 0, 0, 0); \
    }                                                                                  \
  }

__global__ __launch_bounds__(256, 4) void gemm_kernel(const unsigned short* __restrict__ ASW,
                                                      const unsigned short* __restrict__ BSW,
                                                      float* __restrict__ part) {
    __shared__ __align__(16) unsigned short alds[8 * 2048];   // 32 KB: 8 slots x 4 KB
    int tid = threadIdx.x;
    int lane = tid & 63, wave = tid >> 6;
    int tile = blockIdx.x, chunk = blockIdx.y;
    int ks = (chunk * NSTEPS) / KSPLIT;
    int ke = ((chunk + 1) * NSTEPS) / KSPLIT;
    int ln = lane & 15, q = lane >> 4;

    const unsigned short* aswt = ASW + (size_t)tile * NSTEPS * TKELEM;
    const unsigned short* pb = BSW + (size_t)(wave * NSTEPS) * 512 + lane * 8;

    // global source chunk permutation (involution pair with pread below):
    int gsw = (tid & 0xE0) | ((tid & 7) << 2) | ((tid >> 3) & 3);
    int goff = gsw * 8;                        // ushort elements
    // read chunk index: 8-lane groups hit 8 distinct 4-bank groups => conflict-free
    int pread8 = ((((ln >> 3) & 1) << 5) | (q << 3) | (ln & 7)) * 8;
    unsigned short* ldsw = alds + wave * 512;  // this wave's linear 1 KB dest

    floatx4 acc[4][4];   // [frag][sub]
#pragma unroll
    for (int i = 0; i < 4; ++i)
#pragma unroll
        for (int s = 0; s < 4; ++s) acc[i][s] = (floatx4){0.f, 0.f, 0.f, 0.f};

    short8 bA[4], bB[4];

    // prologue: b(ks) + stages ks..ks+6 (chunk length is 32 or 33 >= 8)
#pragma unroll
    for (int i = 0; i < 4; ++i)
        bA[i] = *(const short8*)(pb + ((size_t)(i * 4 * NSTEPS) + ks) * 512);
#pragma unroll
    for (int d = 0; d < 7; ++d)
        __builtin_amdgcn_global_load_lds(
            (const unsigned int*)(aswt + (size_t)(ks + d) * TKELEM + goff),
            (unsigned int*)(ldsw + ((ks + d) & 7) * 2048), 16, 0, 0);

    // peeled head: conservative lower-bound vmcnt immediates (5 ops/window)
    GITER(0,  bA, bB, ks + 0);
    GITER(5,  bB, bA, ks + 1);
    GITER(10, bA, bB, ks + 2);
    GITER(15, bB, bA, ks + 3);
    GITER(20, bA, bB, ks + 4);
    GITER(25, bB, bA, ks + 5);

    int kk = ks + 6;
    for (; kk + 1 < ke; kk += 2) {
        GITER(30, bA, bB, kk);
        GITER(30, bB, bA, kk + 1);
    }
    if (kk < ke) { GITER(30, bA, bB, kk); }

    int row0 = tile * 64;
    float* pbase = part + ((size_t)chunk * PROWS + row0) * 208;
#pragma unroll
    for (int i = 0; i < 4; ++i) {
        int fg = wave + 4 * i;
        if (fg < 13) {
            int c = fg * 16 + ln;
#pragma unroll
            for (int s = 0; s < 4; ++s)
#pragma unroll
                for (int ii = 0; ii < 4; ++ii)
                    pbase[(s * 16 + q * 4 + ii) * 208 + c] = acc[i][s][ii];
        }
    }
}

// ---------------- reduce: out = dinv * sum(partials) + bias ----------------

__global__ __launch_bounds__(256) void reduce_kernel(const float* __restrict__ part,
                                                     const float* __restrict__ dinv,
                                                     const float* __restrict__ bias,
                                                     float* __restrict__ out) {
    int idx = blockIdx.x * blockDim.x + threadIdx.x;
    if (idx >= N_NODES * 50) return;
    int r = idx / 50, cq = idx - r * 50;
    float4 s = {0.f, 0.f, 0.f, 0.f};
#pragma unroll
    for (int c = 0; c < KSPLIT; ++c) {
        float4 v = *(const float4*)(part + ((size_t)c * PROWS + r) * 208 + cq * 4);
        s.x += v.x; s.y += v.y; s.z += v.z; s.w += v.w;
    }
    float dv = dinv[r];
    float4 b = *(const float4*)(bias + cq * 4);
    float4 o;
    o.x = s.x * dv + b.x; o.y = s.y * dv + b.y;
    o.z = s.z * dv + b.z; o.w = s.w * dv + b.w;
    *(float4*)(out + (size_t)r * DIM + cq * 4) = o;
}

// ---------------- launch ----------------

extern "C" void kernel_launch(void* const* d_in, const int* in_sizes, int n_in,
                              void* d_out, int out_size, void* d_ws, size_t ws_size,
                              hipStream_t stream) {
    const float* x      = (const float*)d_in[0];
    const float* weight = (const float*)d_in[1];
    const float* coeff  = (const float*)d_in[2];
    const float* selfw  = (const float*)d_in[3];
    const float* bias   = (const float*)d_in[4];
    const int*   eidx   = (const int*)d_in[5];
    const int*   etype  = (const int*)d_in[6];
    const int* src = eidx;
    const int* tgt = eidx + N_EDGES;
    float* out = (float*)d_out;

    char* ws = (char*)d_ws;
    size_t off = 0;
    auto carve = [&](size_t bytes) {
        char* p = ws + off;
        off += (bytes + 255) & ~(size_t)255;
        return p;
    };
    unsigned short* ASW  = (unsigned short*)carve((size_t)NTILES * NSTEPS * TKELEM * 2);  // 125.4 MB
    unsigned short* BSW  = (unsigned short*)carve((size_t)NFRAG * NSTEPS * 512 * 2);
    float* part   = (float*)carve((size_t)KSPLIT * PROWS * 208 * 4);                      // 50.2 MB
    unsigned short* XbfP = (unsigned short*)carve((size_t)(N_NODES * 224 + 64) * 2);      // 4.5 MB paired
    unsigned int*  Cpair = (unsigned int*)carve((size_t)N_REL * 16 * 4);
    int*   deg    = (int*)carve((size_t)N_NODES * 4);
    int*   starts = (int*)carve((size_t)(N_NODES + 1) * 4);
    int*   cursor = (int*)carve((size_t)N_NODES * 4);
    float* dinv   = (float*)carve((size_t)N_NODES * 4);
    int2*  sedge  = (int2*)carve((size_t)N_EDGES * 8);

    void* fargs[] = {
        (void*)&src, (void*)&tgt, (void*)&etype,
        (void*)&x, (void*)&weight, (void*)&selfw, (void*)&coeff,
        (void*)&deg, (void*)&starts, (void*)&cursor, (void*)&dinv, (void*)&sedge,
        (void*)&XbfP, (void*)&ASW, (void*)&BSW, (void*)&Cpair
    };
    hipLaunchCooperativeKernel((const void*)fused_sort_kernel,
                               dim3(512), dim3(256), fargs, 0, stream);

    agg_kernel<<<N_NODES / 4, 256, 0, stream>>>(
        (const unsigned int*)XbfP, Cpair, starts, sedge, ASW);

    dim3 ggrid(NTILES, KSPLIT);
    gemm_kernel<<<ggrid, 256, 0, stream>>>(ASW, BSW, part);

    reduce_kernel<<<(N_NODES * 50 + 255) / 256, 256, 0, stream>>>(part, dinv, bias, out);
}

// Round 12
// 247.846 us; speedup vs baseline: 1.7432x; 1.7432x over previous
//
#include <hip/hip_runtime.h>
#include <hip/hip_bf16.h>

#define N_NODES 10000
#define N_EDGES 320000
#define N_REL   460
#define N_BASES 30
#define DIM     200
#define KZ      6016   // 30*200=6000 padded to multiple of 32
#define KT      6240   // KZ + 224 (self-term columns appended)
#define NSTEPS  195    // KT/32
#define NTILES  157    // ceil(10000/64)
#define NFRAG   16     // col fragments of 16 (13 real, 3 zero-padded)
#define KSPLIT  8
#define PROWS   10048  // 157*64
#define TKELEM  2048   // ASW elements per (tile,kstep): 4 sub x 16 rows x 32 cols

#define PREP_B8 (NFRAG * NSTEPS * 64)    // 199680 (8 elems/thread)
#define PREP_C  (N_REL * 16)             // 7360
#define PREP_X8 (N_NODES * 28)           // 280000 (28 pair-tasks/node)
#define S1_TOTAL (N_EDGES + PREP_B8 + PREP_C)
#define S2_TOTAL (N_EDGES + PREP_X8)

using short8  = __attribute__((ext_vector_type(8))) short;
using s4v     = __attribute__((ext_vector_type(4))) short;
using floatx4 = __attribute__((ext_vector_type(4))) float;

__device__ __forceinline__ unsigned short f2bf(float f) {
    union { float f; unsigned u; } v; v.f = f;
    unsigned u = v.u;
    return (unsigned short)((u + 0x7fffu + ((u >> 16) & 1u)) >> 16);
}

__device__ __forceinline__ float bf2f(unsigned short s) {
    union { unsigned u; float f; } v;
    v.u = ((unsigned)s) << 16;
    return v.f;
}

__device__ __forceinline__ short8 pack8(const unsigned short* u) {
    union { unsigned short s[8]; short8 v; } p;
#pragma unroll
    for (int i = 0; i < 8; ++i) p.s[i] = u[i];
    return p.v;
}

// ASW v3: 64-row tiles. Element (node n, col c):
//   t=n>>6, sub=(n>>4)&3, rl=n&15; kk=c>>5, w=c&31
//   idx = (t*195+kk)*2048 + sub*512 + rl*32 + w
__device__ __forceinline__ size_t asw_idx(int n, int c) {
    int t = n >> 6, sub = (n >> 4) & 3, rl = n & 15;
    int kk = c >> 5, w = c & 31;
    return (size_t)(t * NSTEPS + kk) * TKELEM + sub * 512 + rl * 32 + w;
}

// ---------------- sort phase 1: hist + independent prep (B, Cpair) ----------------

__global__ void sort1_kernel(const int* __restrict__ tgt, int* __restrict__ deg,
                             const float* __restrict__ weight, const float* __restrict__ sw,
                             const float* __restrict__ coeff,
                             unsigned short* __restrict__ BSW, unsigned int* __restrict__ Cpair) {
    int idx = blockIdx.x * blockDim.x + threadIdx.x;
    if (idx < N_EDGES) {
        atomicAdd(&deg[tgt[idx]], 1);
        return;
    }
    idx -= N_EDGES;
    if (idx < PREP_B8) {
        int f = idx / (NSTEPS * 64);
        int rem = idx - f * (NSTEPS * 64);
        int kk = rem >> 6;
        int l = rem & 63;
        int rB = f * 16 + (l & 15);
        int kbase = kk * 32 + (l >> 4) * 8;
        unsigned short bs[8];
#pragma unroll
        for (int j = 0; j < 8; ++j) {
            int k = kbase + j;
            float v = 0.f;
            if (rB < DIM) {
                if (k < KZ) {
                    if (k < N_BASES * DIM) {
                        int b = k / DIM, kc = k - b * DIM;
                        v = weight[(b * DIM + kc) * DIM + rB];
                    }
                } else {
                    int jj = k - KZ;
                    if (jj < DIM) v = sw[jj * DIM + rB];
                }
            }
            bs[j] = f2bf(v);
        }
        *(short8*)(BSW + (size_t)idx * 8) = pack8(bs);
        return;
    }
    idx -= PREP_B8;
    if (idx < PREP_C) {
        int t = idx >> 4, m = idx & 15;
        unsigned lo = f2bf(coeff[t * N_BASES + m]);
        unsigned hi = (m + 16 < N_BASES) ? f2bf(coeff[t * N_BASES + m + 16]) : 0u;
        Cpair[idx] = lo | (hi << 16);
    }
}

__global__ __launch_bounds__(1024) void scan_kernel(const int* deg, int* starts,
                                                    int* cursor, float* dinv) {
    __shared__ int part[1024];
    int tid = threadIdx.x;
    const int PER = (N_NODES + 1023) / 1024;  // 10
    int base = tid * PER;
    int s = 0;
    for (int i = 0; i < PER; ++i) { int idx = base + i; if (idx < N_NODES) s += deg[idx]; }
    part[tid] = s; __syncthreads();
    for (int off = 1; off < 1024; off <<= 1) {
        int v = (tid >= off) ? part[tid - off] : 0;
        __syncthreads();
        part[tid] += v;
        __syncthreads();
    }
    int run = (tid > 0) ? part[tid - 1] : 0;
    for (int i = 0; i < PER; ++i) {
        int idx = base + i;
        if (idx < N_NODES) {
            int d = deg[idx];
            starts[idx] = run; cursor[idx] = run;
            dinv[idx] = 1.0f / (float)(d > 0 ? d : 1);
            run += d;
        }
    }
    if (tid == 1023) starts[N_NODES] = part[1023];
}

// ---------------- sort phase 2: scatter + deg-dependent prep (XbfP, ASW self) ----------------
// R23 layout (validated R10): XbfP slot (p,c) holds (x[n][p*32+c], x[n][p*32+16+c])
// as (lo,hi) bf16. Cols >= 200 explicit zeros (land only in discarded out cols).

__global__ void sort2_kernel(const int* __restrict__ src, const int* __restrict__ tgt,
                             const int* __restrict__ etype, int* __restrict__ cursor,
                             int2* __restrict__ sedge,
                             const float* __restrict__ x, const int* __restrict__ deg,
                             unsigned short* __restrict__ XbfP, unsigned short* __restrict__ ASW) {
    int idx = blockIdx.x * blockDim.x + threadIdx.x;
    if (idx < N_EDGES) {
        int t = tgt[idx];
        int pos = atomicAdd(&cursor[t], 1);
        sedge[pos] = make_int2(src[idx], etype[idx]);
        return;
    }
    idx -= N_EDGES;
    if (idx < PREP_X8) {
        int n = idx / 28, t = idx - n * 28;
        int p = t >> 2, c4 = (t & 3) << 2;
        int cl = p * 32 + c4;            // lo col base (cl..cl+3)
        int ch = cl + 16;                // hi col base (ch..ch+3)
        int d = deg[n]; if (d < 1) d = 1;
        float df = (float)d;
        floatx4 vlo = (floatx4){0.f, 0.f, 0.f, 0.f};
        floatx4 vhi = (floatx4){0.f, 0.f, 0.f, 0.f};
        if (cl < DIM) vlo = *(const floatx4*)(x + (size_t)n * DIM + cl);
        if (ch < DIM) vhi = *(const floatx4*)(x + (size_t)n * DIM + ch);
        unsigned short xp[8], asl[4], ash[4];
#pragma unroll
        for (int i = 0; i < 4; ++i) {
            xp[2 * i]     = f2bf(vlo[i]);
            xp[2 * i + 1] = f2bf(vhi[i]);
            asl[i] = f2bf(df * vlo[i]);
            ash[i] = f2bf(df * vhi[i]);
        }
        *(short8*)(XbfP + (size_t)n * 224 + p * 32 + c4 * 2) = pack8(xp);
        union { unsigned short s[4]; s4v v; } ul, uh;
#pragma unroll
        for (int i = 0; i < 4; ++i) { ul.s[i] = asl[i]; uh.s[i] = ash[i]; }
        *(s4v*)(ASW + asw_idx(n, KZ + cl)) = ul.v;
        *(s4v*)(ASW + asw_idx(n, KZ + ch)) = uh.v;
    }
}

// ---------------- per-target-node aggregation via MFMA ----------------
// R23 (validated R10): double-buffered gather over PAIRED X: one u32 load
// feeds frags f=2p (lo16) and f=2p+1 (hi16).

__global__ __launch_bounds__(256) void agg_kernel(const unsigned int* __restrict__ XbfP,
                                                  const unsigned int* __restrict__ Cpair,
                                                  const int* __restrict__ starts,
                                                  const int2* __restrict__ sedge,
                                                  unsigned short* __restrict__ ASW) {
    __shared__ __align__(16) unsigned short zbuf[4][3232];  // 25856 B/block
    int lane = threadIdx.x & 63;
    int wave = threadIdx.x >> 6;
    int n = blockIdx.x * 4 + wave;            // 2500*4 == 10000 exactly
    int ln = lane & 15, q = lane >> 4;

    floatx4 acc0[13], acc1[13];
#pragma unroll
    for (int f = 0; f < 13; ++f) {
        acc0[f] = (floatx4){0.f, 0.f, 0.f, 0.f};
        acc1[f] = acc0[f];
    }

    int e0 = starts[n], e1 = starts[n + 1];
    for (int kb = e0; kb < e1; kb += 32) {
        int eb = kb + 8 * q;
        unsigned short a0v[8], a1v[8];
        int srcs[8];
#pragma unroll
        for (int j = 0; j < 8; ++j) {
            int e = eb + j;
            int ec = (e < e1) ? e : (e1 - 1);
            int2 sd = sedge[ec];
            unsigned cp = (e < e1) ? Cpair[sd.y * 16 + ln] : 0u;
            a0v[j] = (unsigned short)(cp & 0xffffu);
            a1v[j] = (unsigned short)(cp >> 16);
            srcs[j] = sd.x;
        }
        short8 A0 = pack8(a0v), A1 = pack8(a1v);

        unsigned pv[2][8];
#pragma unroll
        for (int j = 0; j < 8; ++j)
            pv[0][j] = XbfP[(size_t)srcs[j] * 112 + ln];
#pragma unroll
        for (int p = 0; p < 7; ++p) {
            int cur = p & 1, nxt = cur ^ 1;
            if (p < 6) {
#pragma unroll
                for (int j = 0; j < 8; ++j)
                    pv[nxt][j] = XbfP[(size_t)srcs[j] * 112 + (p + 1) * 16 + ln];
            }
            unsigned short lo[8], hi[8];
#pragma unroll
            for (int j = 0; j < 8; ++j) {
                lo[j] = (unsigned short)(pv[cur][j] & 0xffffu);
                hi[j] = (unsigned short)(pv[cur][j] >> 16);
            }
            short8 Blo = pack8(lo), Bhi = pack8(hi);
            int f0 = 2 * p;
            acc0[f0] = __builtin_amdgcn_mfma_f32_16x16x32_bf16(A0, Blo, acc0[f0], 0, 0, 0);
            acc1[f0] = __builtin_amdgcn_mfma_f32_16x16x32_bf16(A1, Blo, acc1[f0], 0, 0, 0);
            if (2 * p + 1 < 13) {
                acc0[2 * p + 1] = __builtin_amdgcn_mfma_f32_16x16x32_bf16(A0, Bhi, acc0[2 * p + 1], 0, 0, 0);
                acc1[2 * p + 1] = __builtin_amdgcn_mfma_f32_16x16x32_bf16(A1, Bhi, acc1[2 * p + 1], 0, 0, 0);
            }
        }
    }

    unsigned short* zb = zbuf[wave];
    int t = n >> 6, sub = (n >> 4) & 3, rl = n & 15;
    const uint4* zb4 = (const uint4*)zb;
    uint4* dst = (uint4*)ASW;
    size_t base_u4 = (size_t)t * NSTEPS * 256 + sub * 64 + rl * 4;

    // phase 1: bases 0..15 -> cols [0,3200), ksteps 0..99
#pragma unroll
    for (int f = 0; f < 13; ++f) {
        int d = f * 16 + ln;
        if (d < DIM) {
#pragma unroll
            for (int i = 0; i < 4; ++i)
                zb[(q * 4 + i) * DIM + d] = f2bf(acc0[f][i]);
        }
    }
    for (int v = lane; v < 400; v += 64) {
        int kk = v >> 2, w8 = v & 3;
        dst[base_u4 + (size_t)kk * 256 + w8] = zb4[v];
    }

    // phase 2: bases 16..29 -> cols [3200,6000) + pad, ksteps 100..187
    if (lane < 16) zb[2800 + lane] = 0;
#pragma unroll
    for (int f = 0; f < 13; ++f) {
        int d = f * 16 + ln;
        if (d < DIM) {
#pragma unroll
            for (int i = 0; i < 4; ++i) {
                int b1 = 16 + q * 4 + i;
                if (b1 < N_BASES) zb[(b1 - 16) * DIM + d] = f2bf(acc1[f][i]);
            }
        }
    }
    for (int v = lane; v < 352; v += 64) {
        int kk = 100 + (v >> 2), w8 = v & 3;
        dst[base_u4 + (size_t)kk * 256 + w8] = zb4[v];
    }
}

// ---------------- GEMM: part[chunk] = A_ext @ B_ext^T over K-chunk ----------------
// R25: consolidation of 5 rounds of gemm evidence. (a) A-pipeline 8->4 LDS
// slots (16 KB): depth >2 is nullified anyway by the compiler's transitive
// B-wait (vmcnt(6) before each MFMA cluster forces DMAs >=2 iters old — R3),
// so keep depth 3 and take the occupancy instead: 4 blocks/CU now fit by LDS.
// (b) KSPLIT 6->8: 1256 blocks = 4.9/CU feeds that residency (grid was the
// occupancy cap at 942 — R10 Occ 26%). (c) bf16 partials: part 50->33 MB,
// reduce reads halve; fp32 MFMA accumulation unchanged, only the store
// rounds (error ~0.004 after dinv, threshold 0.1125). Head vmcnt immediates
// re-derived for 3 prologue DMAs + 5 VMEM ops/iter: top of iter ks+t has
// {2,6,10} ops after DMA(ks+t); use conservative 0/4/8, steady 8.

#define GITER(VLIT, BU, BL, KK)                                                        \
  {                                                                                    \
    asm volatile("s_waitcnt vmcnt(" #VLIT ")" ::: "memory");                           \
    __builtin_amdgcn_sched_barrier(0);                                                 \
    asm volatile("s_barrier" ::: "memory");                                            \
    const int kk_ = (KK);                                                              \
    const int kld_ = (kk_ + 1 < ke) ? kk_ + 1 : ke - 1;                                \
    BL[0] = *(const short8*)(pb + ((size_t)(0 * 4 * NSTEPS) + kld_) * 512);            \
    BL[1] = *(const short8*)(pb + ((size_t)(1 * 4 * NSTEPS) + kld_) * 512);            \
    BL[2] = *(const short8*)(pb + ((size_t)(2 * 4 * NSTEPS) + kld_) * 512);            \
    BL[3] = *(const short8*)(pb + ((size_t)(3 * 4 * NSTEPS) + kld_) * 512);            \
    const int kst_ = (kk_ + 3 < ke) ? kk_ + 3 : ke - 1;                                \
    __builtin_amdgcn_global_load_lds(                                                  \
        (const unsigned int*)(aswt + (size_t)kst_ * TKELEM + goff),                    \
        (unsigned int*)(ldsw + ((kk_ + 3) & 3) * 2048), 16, 0, 0);                     \
    const unsigned short* sp_ = alds + (kk_ & 3) * 2048 + pread8;                      \
    short8 av0 = *(const short8*)(sp_);                                                \
    short8 av1 = *(const short8*)(sp_ + 512);                                          \
    short8 av2 = *(const short8*)(sp_ + 1024);                                         \
    short8 av3 = *(const short8*)(sp_ + 1536);                                         \
    _Pragma("unroll")                                                                  \
    for (int i_ = 0; i_ < 4; ++i_) {                                                   \
      acc[i_][0] = __builtin_amdgcn_mfma_f32_16x16x32_bf16(av0, BU[i_], acc[i_][0], 0, 0, 0); \
      acc[i_][1] = __builtin_amdgcn_mfma_f32_16x16x32_bf16(av1, BU[i_], acc[i_][1], 0, 0, 0); \
      acc[i_][2] = __builtin_amdgcn_mfma_f32_16x16x32_bf16(av2, BU[i_], acc[i_][2], 0, 0, 0); \
      acc[i_][3] = __builtin_amdgcn_mfma_f32_16x16x32_bf16(av3, BU[i_], acc[i_][3], 0, 0, 0); \
    }                                                                                  \
  }

__global__ __launch_bounds__(256, 4) void gemm_kernel(const unsigned short* __restrict__ ASW,
                                                      const unsigned short* __restrict__ BSW,
                                                      unsigned short* __restrict__ part) {
    __shared__ __align__(16) unsigned short alds[4 * 2048];   // 16 KB: 4 slots x 4 KB
    int tid = threadIdx.x;
    int lane = tid & 63, wave = tid >> 6;
    int tile = blockIdx.x, chunk = blockIdx.y;
    int ks = (chunk * NSTEPS) / KSPLIT;
    int ke = ((chunk + 1) * NSTEPS) / KSPLIT;
    int ln = lane & 15, q = lane >> 4;

    const unsigned short* aswt = ASW + (size_t)tile * NSTEPS * TKELEM;
    const unsigned short* pb = BSW + (size_t)(wave * NSTEPS) * 512 + lane * 8;

    // global source chunk permutation (involution pair with pread below):
    int gsw = (tid & 0xE0) | ((tid & 7) << 2) | ((tid >> 3) & 3);
    int goff = gsw * 8;                        // ushort elements
    // read chunk index: 8-lane groups hit 8 distinct 4-bank groups => conflict-free
    int pread8 = ((((ln >> 3) & 1) << 5) | (q << 3) | (ln & 7)) * 8;
    unsigned short* ldsw = alds + wave * 512;  // this wave's linear 1 KB dest

    floatx4 acc[4][4];   // [frag][sub]
#pragma unroll
    for (int i = 0; i < 4; ++i)
#pragma unroll
        for (int s = 0; s < 4; ++s) acc[i][s] = (floatx4){0.f, 0.f, 0.f, 0.f};

    short8 bA[4], bB[4];

    // prologue: b(ks) + stages ks..ks+2 (chunk length 24 or 25 >= 4)
#pragma unroll
    for (int i = 0; i < 4; ++i)
        bA[i] = *(const short8*)(pb + ((size_t)(i * 4 * NSTEPS) + ks) * 512);
#pragma unroll
    for (int d = 0; d < 3; ++d)
        __builtin_amdgcn_global_load_lds(
            (const unsigned int*)(aswt + (size_t)(ks + d) * TKELEM + goff),
            (unsigned int*)(ldsw + ((ks + d) & 3) * 2048), 16, 0, 0);

    // peeled head: DMA(ks+t) has {2,6,10} VMEM ops after it at top of iter t;
    // conservative immediates 0/4/8 (steady 8)
    GITER(0, bA, bB, ks + 0);
    GITER(4, bB, bA, ks + 1);
    GITER(8, bA, bB, ks + 2);

    int kk = ks + 3;
    for (; kk + 1 < ke; kk += 2) {
        GITER(8, bB, bA, kk);
        GITER(8, bA, bB, kk + 1);
    }
    if (kk < ke) { GITER(8, bB, bA, kk); }

    int row0 = tile * 64;
    unsigned short* pbase = part + ((size_t)chunk * PROWS + row0) * 208;
#pragma unroll
    for (int i = 0; i < 4; ++i) {
        int fg = wave + 4 * i;
        if (fg < 13) {
            int c = fg * 16 + ln;
#pragma unroll
            for (int s = 0; s < 4; ++s)
#pragma unroll
                for (int ii = 0; ii < 4; ++ii)
                    pbase[(s * 16 + q * 4 + ii) * 208 + c] = f2bf(acc[i][s][ii]);
        }
    }
}

// ---------------- reduce: out = dinv * sum(bf16 partials) + bias ----------------

__global__ __launch_bounds__(256) void reduce_kernel(const unsigned short* __restrict__ part,
                                                     const float* __restrict__ dinv,
                                                     const float* __restrict__ bias,
                                                     float* __restrict__ out) {
    int idx = blockIdx.x * blockDim.x + threadIdx.x;
    if (idx >= N_NODES * 50) return;
    int r = idx / 50, cq = idx - r * 50;
    float s0 = 0.f, s1 = 0.f, s2 = 0.f, s3 = 0.f;
#pragma unroll
    for (int c = 0; c < KSPLIT; ++c) {
        union { unsigned short s[4]; s4v v; } u;
        u.v = *(const s4v*)(part + ((size_t)c * PROWS + r) * 208 + cq * 4);
        s0 += bf2f(u.s[0]); s1 += bf2f(u.s[1]);
        s2 += bf2f(u.s[2]); s3 += bf2f(u.s[3]);
    }
    float dv = dinv[r];
    float4 b = *(const float4*)(bias + cq * 4);
    float4 o;
    o.x = s0 * dv + b.x; o.y = s1 * dv + b.y;
    o.z = s2 * dv + b.z; o.w = s3 * dv + b.w;
    *(float4*)(out + (size_t)r * DIM + cq * 4) = o;
}

// ---------------- launch ----------------

extern "C" void kernel_launch(void* const* d_in, const int* in_sizes, int n_in,
                              void* d_out, int out_size, void* d_ws, size_t ws_size,
                              hipStream_t stream) {
    const float* x      = (const float*)d_in[0];
    const float* weight = (const float*)d_in[1];
    const float* coeff  = (const float*)d_in[2];
    const float* selfw  = (const float*)d_in[3];
    const float* bias   = (const float*)d_in[4];
    const int*   eidx   = (const int*)d_in[5];
    const int*   etype  = (const int*)d_in[6];
    const int* src = eidx;
    const int* tgt = eidx + N_EDGES;
    float* out = (float*)d_out;

    char* ws = (char*)d_ws;
    size_t off = 0;
    auto carve = [&](size_t bytes) {
        char* p = ws + off;
        off += (bytes + 255) & ~(size_t)255;
        return p;
    };
    unsigned short* ASW  = (unsigned short*)carve((size_t)NTILES * NSTEPS * TKELEM * 2);  // 125.4 MB
    unsigned short* BSW  = (unsigned short*)carve((size_t)NFRAG * NSTEPS * 512 * 2);
    unsigned short* part = (unsigned short*)carve((size_t)KSPLIT * PROWS * 208 * 2);      // 33.4 MB bf16
    unsigned short* XbfP = (unsigned short*)carve((size_t)(N_NODES * 224 + 64) * 2);      // 4.5 MB paired
    unsigned int*  Cpair = (unsigned int*)carve((size_t)N_REL * 16 * 4);
    int*   deg    = (int*)carve((size_t)N_NODES * 4);
    int*   starts = (int*)carve((size_t)(N_NODES + 1) * 4);
    int*   cursor = (int*)carve((size_t)N_NODES * 4);
    float* dinv   = (float*)carve((size_t)N_NODES * 4);
    int2*  sedge  = (int2*)carve((size_t)N_EDGES * 8);

    hipMemsetAsync(deg, 0, (size_t)N_NODES * 4, stream);

    sort1_kernel<<<(S1_TOTAL + 255) / 256, 256, 0, stream>>>(
        tgt, deg, weight, selfw, coeff, BSW, Cpair);

    scan_kernel<<<1, 1024, 0, stream>>>(deg, starts, cursor, dinv);

    sort2_kernel<<<(S2_TOTAL + 255) / 256, 256, 0, stream>>>(
        src, tgt, etype, cursor, sedge, x, deg, XbfP, ASW);

    agg_kernel<<<N_NODES / 4, 256, 0, stream>>>(
        (const unsigned int*)XbfP, Cpair, starts, sedge, ASW);

    dim3 ggrid(NTILES, KSPLIT);
    gemm_kernel<<<ggrid, 256, 0, stream>>>(ASW, BSW, part);

    reduce_kernel<<<(N_NODES * 50 + 255) / 256, 256, 0, stream>>>(part, dinv, bias, out);
}

// Round 13
// 239.611 us; speedup vs baseline: 1.8031x; 1.0344x over previous
//
#include <hip/hip_runtime.h>
#include <hip/hip_bf16.h>

#define N_NODES 10000
#define N_EDGES 320000
#define N_REL   460
#define N_BASES 30
#define DIM     200
#define KZ      6016   // 30*200=6000 padded to multiple of 32
#define KT      6240   // KZ + 224 (self-term columns appended)
#define NSTEPS  195    // KT/32
#define NTILES  157    // ceil(10000/64)
#define NFRAG   16     // col fragments of 16 (13 real, 3 zero-padded)
#define KSPLIT  8
#define PROWS   10048  // 157*64
#define TKELEM  2048   // ASW elements per (tile,kstep): 4 sub x 16 rows x 32 cols

#define PREP_B8 (NFRAG * NSTEPS * 64)    // 199680 (8 elems/thread)
#define PREP_C  (N_REL * 16)             // 7360
#define PREP_X8 (N_NODES * 28)           // 280000 (28 pair-tasks/node)
#define S1_TOTAL (N_EDGES + PREP_B8 + PREP_C)
#define S2_TOTAL (N_EDGES + PREP_X8)

using short8  = __attribute__((ext_vector_type(8))) short;
using s4v     = __attribute__((ext_vector_type(4))) short;
using floatx4 = __attribute__((ext_vector_type(4))) float;

__device__ __forceinline__ unsigned short f2bf(float f) {
    union { float f; unsigned u; } v; v.f = f;
    unsigned u = v.u;
    return (unsigned short)((u + 0x7fffu + ((u >> 16) & 1u)) >> 16);
}

__device__ __forceinline__ float bf2f(unsigned short s) {
    union { unsigned u; float f; } v;
    v.u = ((unsigned)s) << 16;
    return v.f;
}

__device__ __forceinline__ short8 pack8(const unsigned short* u) {
    union { unsigned short s[8]; short8 v; } p;
#pragma unroll
    for (int i = 0; i < 8; ++i) p.s[i] = u[i];
    return p.v;
}

// ASW v3: 64-row tiles. Element (node n, col c):
//   t=n>>6, sub=(n>>4)&3, rl=n&15; kk=c>>5, w=c&31
//   idx = (t*195+kk)*2048 + sub*512 + rl*32 + w
__device__ __forceinline__ size_t asw_idx(int n, int c) {
    int t = n >> 6, sub = (n >> 4) & 3, rl = n & 15;
    int kk = c >> 5, w = c & 31;
    return (size_t)(t * NSTEPS + kk) * TKELEM + sub * 512 + rl * 32 + w;
}

// ---------------- sort phase 1: hist + independent prep (B, Cpair) ----------------

__global__ void sort1_kernel(const int* __restrict__ tgt, int* __restrict__ deg,
                             const float* __restrict__ weight, const float* __restrict__ sw,
                             const float* __restrict__ coeff,
                             unsigned short* __restrict__ BSW, unsigned int* __restrict__ Cpair) {
    int idx = blockIdx.x * blockDim.x + threadIdx.x;
    if (idx < N_EDGES) {
        atomicAdd(&deg[tgt[idx]], 1);
        return;
    }
    idx -= N_EDGES;
    if (idx < PREP_B8) {
        int f = idx / (NSTEPS * 64);
        int rem = idx - f * (NSTEPS * 64);
        int kk = rem >> 6;
        int l = rem & 63;
        int rB = f * 16 + (l & 15);
        int kbase = kk * 32 + (l >> 4) * 8;
        unsigned short bs[8];
#pragma unroll
        for (int j = 0; j < 8; ++j) {
            int k = kbase + j;
            float v = 0.f;
            if (rB < DIM) {
                if (k < KZ) {
                    if (k < N_BASES * DIM) {
                        int b = k / DIM, kc = k - b * DIM;
                        v = weight[(b * DIM + kc) * DIM + rB];
                    }
                } else {
                    int jj = k - KZ;
                    if (jj < DIM) v = sw[jj * DIM + rB];
                }
            }
            bs[j] = f2bf(v);
        }
        *(short8*)(BSW + (size_t)idx * 8) = pack8(bs);
        return;
    }
    idx -= PREP_B8;
    if (idx < PREP_C) {
        int t = idx >> 4, m = idx & 15;
        unsigned lo = f2bf(coeff[t * N_BASES + m]);
        unsigned hi = (m + 16 < N_BASES) ? f2bf(coeff[t * N_BASES + m + 16]) : 0u;
        Cpair[idx] = lo | (hi << 16);
    }
}

__global__ __launch_bounds__(1024) void scan_kernel(const int* deg, int* starts,
                                                    int* cursor, float* dinv) {
    __shared__ int part[1024];
    int tid = threadIdx.x;
    const int PER = (N_NODES + 1023) / 1024;  // 10
    int base = tid * PER;
    int s = 0;
    for (int i = 0; i < PER; ++i) { int idx = base + i; if (idx < N_NODES) s += deg[idx]; }
    part[tid] = s; __syncthreads();
    for (int off = 1; off < 1024; off <<= 1) {
        int v = (tid >= off) ? part[tid - off] : 0;
        __syncthreads();
        part[tid] += v;
        __syncthreads();
    }
    int run = (tid > 0) ? part[tid - 1] : 0;
    for (int i = 0; i < PER; ++i) {
        int idx = base + i;
        if (idx < N_NODES) {
            int d = deg[idx];
            starts[idx] = run; cursor[idx] = run;
            dinv[idx] = 1.0f / (float)(d > 0 ? d : 1);
            run += d;
        }
    }
    if (tid == 1023) starts[N_NODES] = part[1023];
}

// ---------------- sort phase 2: scatter + deg-dependent prep (XbfP, ASW self) ----------------
// R23 layout (validated R10): XbfP slot (p,c) holds (x[n][p*32+c], x[n][p*32+16+c])
// as (lo,hi) bf16. Cols >= 200 explicit zeros (land only in discarded out cols).

__global__ void sort2_kernel(const int* __restrict__ src, const int* __restrict__ tgt,
                             const int* __restrict__ etype, int* __restrict__ cursor,
                             int2* __restrict__ sedge,
                             const float* __restrict__ x, const int* __restrict__ deg,
                             unsigned short* __restrict__ XbfP, unsigned short* __restrict__ ASW) {
    int idx = blockIdx.x * blockDim.x + threadIdx.x;
    if (idx < N_EDGES) {
        int t = tgt[idx];
        int pos = atomicAdd(&cursor[t], 1);
        sedge[pos] = make_int2(src[idx], etype[idx]);
        return;
    }
    idx -= N_EDGES;
    if (idx < PREP_X8) {
        int n = idx / 28, t = idx - n * 28;
        int p = t >> 2, c4 = (t & 3) << 2;
        int cl = p * 32 + c4;            // lo col base (cl..cl+3)
        int ch = cl + 16;                // hi col base (ch..ch+3)
        int d = deg[n]; if (d < 1) d = 1;
        float df = (float)d;
        floatx4 vlo = (floatx4){0.f, 0.f, 0.f, 0.f};
        floatx4 vhi = (floatx4){0.f, 0.f, 0.f, 0.f};
        if (cl < DIM) vlo = *(const floatx4*)(x + (size_t)n * DIM + cl);
        if (ch < DIM) vhi = *(const floatx4*)(x + (size_t)n * DIM + ch);
        unsigned short xp[8], asl[4], ash[4];
#pragma unroll
        for (int i = 0; i < 4; ++i) {
            xp[2 * i]     = f2bf(vlo[i]);
            xp[2 * i + 1] = f2bf(vhi[i]);
            asl[i] = f2bf(df * vlo[i]);
            ash[i] = f2bf(df * vhi[i]);
        }
        *(short8*)(XbfP + (size_t)n * 224 + p * 32 + c4 * 2) = pack8(xp);
        union { unsigned short s[4]; s4v v; } ul, uh;
#pragma unroll
        for (int i = 0; i < 4; ++i) { ul.s[i] = asl[i]; uh.s[i] = ash[i]; }
        *(s4v*)(ASW + asw_idx(n, KZ + cl)) = ul.v;
        *(s4v*)(ASW + asw_idx(n, KZ + ch)) = uh.v;
    }
}

// ---------------- per-target-node aggregation via MFMA ----------------
// R26: each node is split across TWO waves by coefficient half: h=0 computes
// the old acc0 (bases 0-15, A = Cpair lo16), h=1 the old acc1 (bases 16-29,
// A = hi16). Rationale: agg was latency-bound at Occ 15.6% with VGPR=112
// (26 accumulators = the VGPR wall); per-wave acc halves to 13 (52 VGPR),
// wave count doubles (grid 2500->5000 blocks). Gather stream duplicated
// across the node's two waves (XbfP/Cpair are L1/L2-resident). Per
// accumulator the MFMA set and order are identical to R12 => bit-identical.
// Epilogue: h=0 = old phase-1 (ksteps 0..99), h=1 = old phase-2 (100..187).

__global__ __launch_bounds__(256) void agg_kernel(const unsigned int* __restrict__ XbfP,
                                                  const unsigned int* __restrict__ Cpair,
                                                  const int* __restrict__ starts,
                                                  const int2* __restrict__ sedge,
                                                  unsigned short* __restrict__ ASW) {
    __shared__ __align__(16) unsigned short zbuf[4][3232];  // 25856 B/block
    int lane = threadIdx.x & 63;
    int wave = threadIdx.x >> 6;
    int n = blockIdx.x * 2 + (wave >> 1);     // 5000*2 == 10000 exactly
    int h = wave & 1;                         // 0: bases 0-15, 1: bases 16-29
    int ln = lane & 15, q = lane >> 4;

    floatx4 acc[13];
#pragma unroll
    for (int f = 0; f < 13; ++f) acc[f] = (floatx4){0.f, 0.f, 0.f, 0.f};

    int e0 = starts[n], e1 = starts[n + 1];
    for (int kb = e0; kb < e1; kb += 32) {
        int eb = kb + 8 * q;
        unsigned short av[8];
        int srcs[8];
#pragma unroll
        for (int j = 0; j < 8; ++j) {
            int e = eb + j;
            int ec = (e < e1) ? e : (e1 - 1);
            int2 sd = sedge[ec];
            unsigned cp = (e < e1) ? Cpair[sd.y * 16 + ln] : 0u;
            av[j] = h ? (unsigned short)(cp >> 16) : (unsigned short)(cp & 0xffffu);
            srcs[j] = sd.x;
        }
        short8 A = pack8(av);

        unsigned pv[2][8];
#pragma unroll
        for (int j = 0; j < 8; ++j)
            pv[0][j] = XbfP[(size_t)srcs[j] * 112 + ln];
#pragma unroll
        for (int p = 0; p < 7; ++p) {
            int cur = p & 1, nxt = cur ^ 1;
            if (p < 6) {
#pragma unroll
                for (int j = 0; j < 8; ++j)
                    pv[nxt][j] = XbfP[(size_t)srcs[j] * 112 + (p + 1) * 16 + ln];
            }
            unsigned short lo[8], hi[8];
#pragma unroll
            for (int j = 0; j < 8; ++j) {
                lo[j] = (unsigned short)(pv[cur][j] & 0xffffu);
                hi[j] = (unsigned short)(pv[cur][j] >> 16);
            }
            short8 Blo = pack8(lo), Bhi = pack8(hi);
            int f0 = 2 * p;
            acc[f0] = __builtin_amdgcn_mfma_f32_16x16x32_bf16(A, Blo, acc[f0], 0, 0, 0);
            if (2 * p + 1 < 13)
                acc[2 * p + 1] = __builtin_amdgcn_mfma_f32_16x16x32_bf16(A, Bhi, acc[2 * p + 1], 0, 0, 0);
        }
    }

    unsigned short* zb = zbuf[wave];
    int t = n >> 6, sub = (n >> 4) & 3, rl = n & 15;
    const uint4* zb4 = (const uint4*)zb;
    uint4* dst = (uint4*)ASW;
    size_t base_u4 = (size_t)t * NSTEPS * 256 + sub * 64 + rl * 4;

    if (h == 0) {
        // bases 0..15 -> cols [0,3200), ksteps 0..99
#pragma unroll
        for (int f = 0; f < 13; ++f) {
            int d = f * 16 + ln;
            if (d < DIM) {
#pragma unroll
                for (int i = 0; i < 4; ++i)
                    zb[(q * 4 + i) * DIM + d] = f2bf(acc[f][i]);
            }
        }
        for (int v = lane; v < 400; v += 64) {
            int kk = v >> 2, w8 = v & 3;
            dst[base_u4 + (size_t)kk * 256 + w8] = zb4[v];
        }
    } else {
        // bases 16..29 -> cols [3200,6000) + pad, ksteps 100..187
        if (lane < 16) zb[2800 + lane] = 0;
#pragma unroll
        for (int f = 0; f < 13; ++f) {
            int d = f * 16 + ln;
            if (d < DIM) {
#pragma unroll
                for (int i = 0; i < 4; ++i) {
                    int b1 = 16 + q * 4 + i;
                    if (b1 < N_BASES) zb[(q * 4 + i) * DIM + d] = f2bf(acc[f][i]);
                }
            }
        }
        for (int v = lane; v < 352; v += 64) {
            int kk = 100 + (v >> 2), w8 = v & 3;
            dst[base_u4 + (size_t)kk * 256 + w8] = zb4[v];
        }
    }
}

// ---------------- GEMM: part[chunk] = A_ext @ B_ext^T over K-chunk ----------------
// R25 (validated R12: dropped out of top-5). A staged via global_load_lds,
// 4 LDS slots (16 KB), KSPLIT=8, bf16 partials; depth-3 pipeline with
// conservative head immediates 0/4/8, steady vmcnt(8).

#define GITER(VLIT, BU, BL, KK)                                                        \
  {                                                                                    \
    asm volatile("s_waitcnt vmcnt(" #VLIT ")" ::: "memory");                           \
    __builtin_amdgcn_sched_barrier(0);                                                 \
    asm volatile("s_barrier" ::: "memory");                                            \
    const int kk_ = (KK);                                                              \
    const int kld_ = (kk_ + 1 < ke) ? kk_ + 1 : ke - 1;                                \
    BL[0] = *(const short8*)(pb + ((size_t)(0 * 4 * NSTEPS) + kld_) * 512);            \
    BL[1] = *(const short8*)(pb + ((size_t)(1 * 4 * NSTEPS) + kld_) * 512);            \
    BL[2] = *(const short8*)(pb + ((size_t)(2 * 4 * NSTEPS) + kld_) * 512);            \
    BL[3] = *(const short8*)(pb + ((size_t)(3 * 4 * NSTEPS) + kld_) * 512);            \
    const int kst_ = (kk_ + 3 < ke) ? kk_ + 3 : ke - 1;                                \
    __builtin_amdgcn_global_load_lds(                                                  \
        (const unsigned int*)(aswt + (size_t)kst_ * TKELEM + goff),                    \
        (unsigned int*)(ldsw + ((kk_ + 3) & 3) * 2048), 16, 0, 0);                     \
    const unsigned short* sp_ = alds + (kk_ & 3) * 2048 + pread8;                      \
    short8 av0 = *(const short8*)(sp_);                                                \
    short8 av1 = *(const short8*)(sp_ + 512);                                          \
    short8 av2 = *(const short8*)(sp_ + 1024);                                         \
    short8 av3 = *(const short8*)(sp_ + 1536);                                         \
    _Pragma("unroll")                                                                  \
    for (int i_ = 0; i_ < 4; ++i_) {                                                   \
      acc[i_][0] = __builtin_amdgcn_mfma_f32_16x16x32_bf16(av0, BU[i_], acc[i_][0], 0, 0, 0); \
      acc[i_][1] = __builtin_amdgcn_mfma_f32_16x16x32_bf16(av1, BU[i_], acc[i_][1], 0, 0, 0); \
      acc[i_][2] = __builtin_amdgcn_mfma_f32_16x16x32_bf16(av2, BU[i_], acc[i_][2], 0, 0, 0); \
      acc[i_][3] = __builtin_amdgcn_mfma_f32_16x16x32_bf16(av3, BU[i_], acc[i_][3], 0, 0, 0); \
    }                                                                                  \
  }

__global__ __launch_bounds__(256, 4) void gemm_kernel(const unsigned short* __restrict__ ASW,
                                                      const unsigned short* __restrict__ BSW,
                                                      unsigned short* __restrict__ part) {
    __shared__ __align__(16) unsigned short alds[4 * 2048];   // 16 KB: 4 slots x 4 KB
    int tid = threadIdx.x;
    int lane = tid & 63, wave = tid >> 6;
    int tile = blockIdx.x, chunk = blockIdx.y;
    int ks = (chunk * NSTEPS) / KSPLIT;
    int ke = ((chunk + 1) * NSTEPS) / KSPLIT;
    int ln = lane & 15, q = lane >> 4;

    const unsigned short* aswt = ASW + (size_t)tile * NSTEPS * TKELEM;
    const unsigned short* pb = BSW + (size_t)(wave * NSTEPS) * 512 + lane * 8;

    // global source chunk permutation (involution pair with pread below):
    int gsw = (tid & 0xE0) | ((tid & 7) << 2) | ((tid >> 3) & 3);
    int goff = gsw * 8;                        // ushort elements
    // read chunk index: 8-lane groups hit 8 distinct 4-bank groups => conflict-free
    int pread8 = ((((ln >> 3) & 1) << 5) | (q << 3) | (ln & 7)) * 8;
    unsigned short* ldsw = alds + wave * 512;  // this wave's linear 1 KB dest

    floatx4 acc[4][4];   // [frag][sub]
#pragma unroll
    for (int i = 0; i < 4; ++i)
#pragma unroll
        for (int s = 0; s < 4; ++s) acc[i][s] = (floatx4){0.f, 0.f, 0.f, 0.f};

    short8 bA[4], bB[4];

    // prologue: b(ks) + stages ks..ks+2 (chunk length 24 or 25 >= 4)
#pragma unroll
    for (int i = 0; i < 4; ++i)
        bA[i] = *(const short8*)(pb + ((size_t)(i * 4 * NSTEPS) + ks) * 512);
#pragma unroll
    for (int d = 0; d < 3; ++d)
        __builtin_amdgcn_global_load_lds(
            (const unsigned int*)(aswt + (size_t)(ks + d) * TKELEM + goff),
            (unsigned int*)(ldsw + ((ks + d) & 3) * 2048), 16, 0, 0);

    // peeled head: DMA(ks+t) has {2,6,10} VMEM ops after it at top of iter t;
    // conservative immediates 0/4/8 (steady 8)
    GITER(0, bA, bB, ks + 0);
    GITER(4, bB, bA, ks + 1);
    GITER(8, bA, bB, ks + 2);

    int kk = ks + 3;
    for (; kk + 1 < ke; kk += 2) {
        GITER(8, bB, bA, kk);
        GITER(8, bA, bB, kk + 1);
    }
    if (kk < ke) { GITER(8, bB, bA, kk); }

    int row0 = tile * 64;
    unsigned short* pbase = part + ((size_t)chunk * PROWS + row0) * 208;
#pragma unroll
    for (int i = 0; i < 4; ++i) {
        int fg = wave + 4 * i;
        if (fg < 13) {
            int c = fg * 16 + ln;
#pragma unroll
            for (int s = 0; s < 4; ++s)
#pragma unroll
                for (int ii = 0; ii < 4; ++ii)
                    pbase[(s * 16 + q * 4 + ii) * 208 + c] = f2bf(acc[i][s][ii]);
        }
    }
}

// ---------------- reduce: out = dinv * sum(bf16 partials) + bias ----------------

__global__ __launch_bounds__(256) void reduce_kernel(const unsigned short* __restrict__ part,
                                                     const float* __restrict__ dinv,
                                                     const float* __restrict__ bias,
                                                     float* __restrict__ out) {
    int idx = blockIdx.x * blockDim.x + threadIdx.x;
    if (idx >= N_NODES * 50) return;
    int r = idx / 50, cq = idx - r * 50;
    float s0 = 0.f, s1 = 0.f, s2 = 0.f, s3 = 0.f;
#pragma unroll
    for (int c = 0; c < KSPLIT; ++c) {
        union { unsigned short s[4]; s4v v; } u;
        u.v = *(const s4v*)(part + ((size_t)c * PROWS + r) * 208 + cq * 4);
        s0 += bf2f(u.s[0]); s1 += bf2f(u.s[1]);
        s2 += bf2f(u.s[2]); s3 += bf2f(u.s[3]);
    }
    float dv = dinv[r];
    float4 b = *(const float4*)(bias + cq * 4);
    float4 o;
    o.x = s0 * dv + b.x; o.y = s1 * dv + b.y;
    o.z = s2 * dv + b.z; o.w = s3 * dv + b.w;
    *(float4*)(out + (size_t)r * DIM + cq * 4) = o;
}

// ---------------- launch ----------------

extern "C" void kernel_launch(void* const* d_in, const int* in_sizes, int n_in,
                              void* d_out, int out_size, void* d_ws, size_t ws_size,
                              hipStream_t stream) {
    const float* x      = (const float*)d_in[0];
    const float* weight = (const float*)d_in[1];
    const float* coeff  = (const float*)d_in[2];
    const float* selfw  = (const float*)d_in[3];
    const float* bias   = (const float*)d_in[4];
    const int*   eidx   = (const int*)d_in[5];
    const int*   etype  = (const int*)d_in[6];
    const int* src = eidx;
    const int* tgt = eidx + N_EDGES;
    float* out = (float*)d_out;

    char* ws = (char*)d_ws;
    size_t off = 0;
    auto carve = [&](size_t bytes) {
        char* p = ws + off;
        off += (bytes + 255) & ~(size_t)255;
        return p;
    };
    unsigned short* ASW  = (unsigned short*)carve((size_t)NTILES * NSTEPS * TKELEM * 2);  // 125.4 MB
    unsigned short* BSW  = (unsigned short*)carve((size_t)NFRAG * NSTEPS * 512 * 2);
    unsigned short* part = (unsigned short*)carve((size_t)KSPLIT * PROWS * 208 * 2);      // 33.4 MB bf16
    unsigned short* XbfP = (unsigned short*)carve((size_t)(N_NODES * 224 + 64) * 2);      // 4.5 MB paired
    unsigned int*  Cpair = (unsigned int*)carve((size_t)N_REL * 16 * 4);
    int*   deg    = (int*)carve((size_t)N_NODES * 4);
    int*   starts = (int*)carve((size_t)(N_NODES + 1) * 4);
    int*   cursor = (int*)carve((size_t)N_NODES * 4);
    float* dinv   = (float*)carve((size_t)N_NODES * 4);
    int2*  sedge  = (int2*)carve((size_t)N_EDGES * 8);

    hipMemsetAsync(deg, 0, (size_t)N_NODES * 4, stream);

    sort1_kernel<<<(S1_TOTAL + 255) / 256, 256, 0, stream>>>(
        tgt, deg, weight, selfw, coeff, BSW, Cpair);

    scan_kernel<<<1, 1024, 0, stream>>>(deg, starts, cursor, dinv);

    sort2_kernel<<<(S2_TOTAL + 255) / 256, 256, 0, stream>>>(
        src, tgt, etype, cursor, sedge, x, deg, XbfP, ASW);

    agg_kernel<<<N_NODES / 2, 256, 0, stream>>>(
        (const unsigned int*)XbfP, Cpair, starts, sedge, ASW);

    dim3 ggrid(NTILES, KSPLIT);
    gemm_kernel<<<ggrid, 256, 0, stream>>>(ASW, BSW, part);

    reduce_kernel<<<(N_NODES * 50 + 255) / 256, 256, 0, stream>>>(part, dinv, bias, out);
}